// Round 6
// baseline (125.965 us; speedup 1.0000x reference)
//
#include <hip/hip_runtime.h>
#include <hip/hip_cooperative_groups.h>
#include <math.h>

#define BB 4
#define NN 256
#define FCH 512
#define GCH 256
#define HID 128
#define ROWS 1024

namespace cg = cooperative_groups;

// ---------------- phase A: projection, no LDS staging ----------------
// block covers 8 rows x all 128 h; K-split 4 (kq = t>>7).
// Input row reads are wave-uniform -> scalar (SMEM) broadcast loads.
// W[c*128+h]: 64 consecutive lanes -> 256B coalesced; W read once per block.
template <int INCH>
__device__ __forceinline__ void proj_phaseA(const float* __restrict__ in,
                                            const float* __restrict__ W,
                                            const float* __restrict__ bias,
                                            float* __restrict__ dst,
                                            int r0, int t,
                                            float* __restrict__ lds) {
    const int kq = t >> 7;              // 0..3
    const int h  = t & 127;
    constexpr int cpk = INCH / 4;       // f:128 g:64
    const int c0 = kq * cpk;

    float acc[8] = {0.f, 0.f, 0.f, 0.f, 0.f, 0.f, 0.f, 0.f};

    #pragma unroll 2
    for (int cc = 0; cc < cpk; cc += 4) {
        const int c = c0 + cc;
        const float4 s0 = *(const float4*)&in[(size_t)(r0 + 0) * INCH + c];
        const float4 s1 = *(const float4*)&in[(size_t)(r0 + 1) * INCH + c];
        const float4 s2 = *(const float4*)&in[(size_t)(r0 + 2) * INCH + c];
        const float4 s3 = *(const float4*)&in[(size_t)(r0 + 3) * INCH + c];
        const float4 s4 = *(const float4*)&in[(size_t)(r0 + 4) * INCH + c];
        const float4 s5 = *(const float4*)&in[(size_t)(r0 + 5) * INCH + c];
        const float4 s6 = *(const float4*)&in[(size_t)(r0 + 6) * INCH + c];
        const float4 s7 = *(const float4*)&in[(size_t)(r0 + 7) * INCH + c];
        const float w0 = W[(size_t)(c + 0) * HID + h];
        const float w1 = W[(size_t)(c + 1) * HID + h];
        const float w2 = W[(size_t)(c + 2) * HID + h];
        const float w3 = W[(size_t)(c + 3) * HID + h];
        acc[0] = fmaf(s0.x, w0, acc[0]); acc[0] = fmaf(s0.y, w1, acc[0]);
        acc[0] = fmaf(s0.z, w2, acc[0]); acc[0] = fmaf(s0.w, w3, acc[0]);
        acc[1] = fmaf(s1.x, w0, acc[1]); acc[1] = fmaf(s1.y, w1, acc[1]);
        acc[1] = fmaf(s1.z, w2, acc[1]); acc[1] = fmaf(s1.w, w3, acc[1]);
        acc[2] = fmaf(s2.x, w0, acc[2]); acc[2] = fmaf(s2.y, w1, acc[2]);
        acc[2] = fmaf(s2.z, w2, acc[2]); acc[2] = fmaf(s2.w, w3, acc[2]);
        acc[3] = fmaf(s3.x, w0, acc[3]); acc[3] = fmaf(s3.y, w1, acc[3]);
        acc[3] = fmaf(s3.z, w2, acc[3]); acc[3] = fmaf(s3.w, w3, acc[3]);
        acc[4] = fmaf(s4.x, w0, acc[4]); acc[4] = fmaf(s4.y, w1, acc[4]);
        acc[4] = fmaf(s4.z, w2, acc[4]); acc[4] = fmaf(s4.w, w3, acc[4]);
        acc[5] = fmaf(s5.x, w0, acc[5]); acc[5] = fmaf(s5.y, w1, acc[5]);
        acc[5] = fmaf(s5.z, w2, acc[5]); acc[5] = fmaf(s5.w, w3, acc[5]);
        acc[6] = fmaf(s6.x, w0, acc[6]); acc[6] = fmaf(s6.y, w1, acc[6]);
        acc[6] = fmaf(s6.z, w2, acc[6]); acc[6] = fmaf(s6.w, w3, acc[6]);
        acc[7] = fmaf(s7.x, w0, acc[7]); acc[7] = fmaf(s7.y, w1, acc[7]);
        acc[7] = fmaf(s7.z, w2, acc[7]); acc[7] = fmaf(s7.w, w3, acc[7]);
    }

    // partial[kq][r][h]
    #pragma unroll
    for (int r = 0; r < 8; ++r) lds[(kq * 8 + r) * 128 + h] = acc[r];
    __syncthreads();

    // combine: 1024 outputs (r,h), 512 threads -> 2 each
    #pragma unroll
    for (int i = 0; i < 2; ++i) {
        const int idx = t + i * 512;
        const int r = idx >> 7;
        const int hh = idx & 127;
        const float v = bias[hh]
                      + lds[(0 * 8 + r) * 128 + hh] + lds[(1 * 8 + r) * 128 + hh]
                      + lds[(2 * 8 + r) * 128 + hh] + lds[(3 * 8 + r) * 128 + hh];
        dst[(size_t)(r0 + r) * HID + hh] = v;
    }
}

// ---------------- fused kernel: proj -> grid sync -> att+softmax ----------------
#define HS 8
#define USTR 36
#define UIDX_OFF(j, hs, off) ((j) * (HS * USTR) + (hs) * USTR + (off))

__global__ __launch_bounds__(512, 2) void fused_kernel(
    const float* __restrict__ feat, const float* __restrict__ gfeat,
    const float* __restrict__ adj,
    const float* __restrict__ Wf, const float* __restrict__ bf,
    const float* __restrict__ Wg, const float* __restrict__ bg,
    const float* __restrict__ Cf, const float* __restrict__ Cg,
    const float* __restrict__ a_w,
    float* __restrict__ pf, float* __restrict__ pg,
    float* __restrict__ scfg, float* __restrict__ out)
{
    __shared__ __align__(16) float pool[5632];   // 22.5 KB, reused across phases
    const int t = threadIdx.x;
    const int bx = blockIdx.x;

    // ---- phase A: projection (f: blocks 0-127, g: blocks 128-255) ----
    if (bx < 128) proj_phaseA<FCH>(feat, Wf, bf, pf, bx * 8, t, pool);
    else          proj_phaseA<GCH>(gfeat, Wg, bg, pg, (bx - 128) * 8, t, pool);

    // ---- scf/scg on the two lightest blocks (g-blocks finish phase A early) ----
    if (bx >= 254) {
        const float* __restrict__ C = (bx == 254) ? Cf : Cg;
        float* __restrict__ dstv = scfg + ((bx == 254) ? 0 : HID);
        const int h = t & 127;
        const int ks = t >> 7;
        float a = 0.f;
        #pragma unroll 4
        for (int i = 0; i < 32; ++i) {
            const int k = ks * 32 + i;
            a = fmaf(a_w[k], C[k * HID + h], a);
        }
        pool[4096 + ks * 128 + h] = a;   // disjoint from proj's [0,4096)
        __syncthreads();
        if (t < 128)
            dstv[t] = pool[4096 + t] + pool[4096 + 128 + t]
                    + pool[4096 + 256 + t] + pool[4096 + 384 + t];
    }

    __threadfence();
    cg::this_grid().sync();

    // ---- phase B: att + masked softmax (4n x 4m register tile) ----
    float* __restrict__ ufc   = pool;
    float* __restrict__ uf2s  = pool + 1152;
    float* __restrict__ ugc   = pool + 2304;
    float* __restrict__ ug2s  = pool + 3456;
    float* __restrict__ att_s = pool + 4608;     // [4][256]

    const int b = bx >> 6;
    const int n0 = (bx & 63) * 4;

    {
        const int j = t >> 7;
        const int h = t & (HID - 1);
        const float sf = scfg[h];
        const float sg = scfg[HID + h];
        const float uf = pf[(size_t)(b * NN + n0 + j) * HID + h];
        const float ug = pg[(size_t)(b * NN + n0 + j) * HID + h];
        const int ui = UIDX_OFF(j, h >> 4, h & 15);
        ufc[ui]  = uf * sf;
        uf2s[ui] = uf * uf;
        ugc[ui]  = ug * sg;
        ug2s[ui] = ug * ug;
    }
    __syncthreads();

    const int hs = t & 7;
    const int mg = t >> 3;
    const int m0 = mg * 4;
    const int hbase = hs * 16;

    float numf[4][4] = {}, denf[4][4] = {}, numg[4][4] = {}, deng[4][4] = {};

    #pragma unroll
    for (int it = 0; it < 4; ++it) {
        const int h = hbase + it * 4;
        float4 vf[4], vg[4], wf[4], wg[4];
        #pragma unroll
        for (int k = 0; k < 4; ++k) {
            vf[k] = *(const float4*)&pf[(size_t)(b * NN + m0 + k) * HID + h];
            vg[k] = *(const float4*)&pg[(size_t)(b * NN + m0 + k) * HID + h];
            wf[k].x = vf[k].x * vf[k].x; wf[k].y = vf[k].y * vf[k].y;
            wf[k].z = vf[k].z * vf[k].z; wf[k].w = vf[k].w * vf[k].w;
            wg[k].x = vg[k].x * vg[k].x; wg[k].y = vg[k].y * vg[k].y;
            wg[k].z = vg[k].z * vg[k].z; wg[k].w = vg[k].w * vg[k].w;
        }
        #pragma unroll
        for (int j = 0; j < 4; ++j) {
            const int ui = UIDX_OFF(j, hs, it * 4);
            const float4 c = *(const float4*)&ufc[ui];
            const float4 q = *(const float4*)&uf2s[ui];
            const float4 d = *(const float4*)&ugc[ui];
            const float4 r = *(const float4*)&ug2s[ui];
            #pragma unroll
            for (int k = 0; k < 4; ++k) {
                numf[j][k] = fmaf(vf[k].x, c.x, numf[j][k]);
                numf[j][k] = fmaf(vf[k].y, c.y, numf[j][k]);
                numf[j][k] = fmaf(vf[k].z, c.z, numf[j][k]);
                numf[j][k] = fmaf(vf[k].w, c.w, numf[j][k]);
                denf[j][k] = fmaf(wf[k].x, q.x, denf[j][k]);
                denf[j][k] = fmaf(wf[k].y, q.y, denf[j][k]);
                denf[j][k] = fmaf(wf[k].z, q.z, denf[j][k]);
                denf[j][k] = fmaf(wf[k].w, q.w, denf[j][k]);
                numg[j][k] = fmaf(vg[k].x, d.x, numg[j][k]);
                numg[j][k] = fmaf(vg[k].y, d.y, numg[j][k]);
                numg[j][k] = fmaf(vg[k].z, d.z, numg[j][k]);
                numg[j][k] = fmaf(vg[k].w, d.w, numg[j][k]);
                deng[j][k] = fmaf(wg[k].x, r.x, deng[j][k]);
                deng[j][k] = fmaf(wg[k].y, r.y, deng[j][k]);
                deng[j][k] = fmaf(wg[k].z, r.z, deng[j][k]);
                deng[j][k] = fmaf(wg[k].w, r.w, deng[j][k]);
            }
        }
    }

    #pragma unroll
    for (int j = 0; j < 4; ++j) {
        #pragma unroll
        for (int k = 0; k < 4; ++k) {
            #pragma unroll
            for (int off = 1; off < 8; off <<= 1) {
                numf[j][k] += __shfl_xor(numf[j][k], off, 8);
                denf[j][k] += __shfl_xor(denf[j][k], off, 8);
                numg[j][k] += __shfl_xor(numg[j][k], off, 8);
                deng[j][k] += __shfl_xor(deng[j][k], off, 8);
            }
        }
    }

    if (hs == 0) {
        #pragma unroll
        for (int j = 0; j < 4; ++j) {
            const float4 ad = *(const float4*)&adj[(size_t)(b * NN + n0 + j) * NN + m0];
            float4 a4;
            a4.x = numf[j][0] / fmaxf(sqrtf(denf[j][0]), 1e-12f) + numg[j][0] / fmaxf(sqrtf(deng[j][0]), 1e-12f);
            a4.y = numf[j][1] / fmaxf(sqrtf(denf[j][1]), 1e-12f) + numg[j][1] / fmaxf(sqrtf(deng[j][1]), 1e-12f);
            a4.z = numf[j][2] / fmaxf(sqrtf(denf[j][2]), 1e-12f) + numg[j][2] / fmaxf(sqrtf(deng[j][2]), 1e-12f);
            a4.w = numf[j][3] / fmaxf(sqrtf(denf[j][3]), 1e-12f) + numg[j][3] / fmaxf(sqrtf(deng[j][3]), 1e-12f);
            if (ad.x == 0.f) a4.x -= 1e22f;
            if (ad.y == 0.f) a4.y -= 1e22f;
            if (ad.z == 0.f) a4.z -= 1e22f;
            if (ad.w == 0.f) a4.w -= 1e22f;
            *(float4*)&att_s[j * NN + m0] = a4;
        }
    }
    __syncthreads();

    const int w = t >> 6;
    const int lane = t & 63;
    if (w < 4) {
        const float4 v = *(const float4*)&att_s[w * NN + lane * 4];
        float mx = fmaxf(fmaxf(v.x, v.y), fmaxf(v.z, v.w));
        #pragma unroll
        for (int off = 1; off < 64; off <<= 1) mx = fmaxf(mx, __shfl_xor(mx, off, 64));
        float4 e;
        e.x = __expf(v.x - mx); e.y = __expf(v.y - mx);
        e.z = __expf(v.z - mx); e.w = __expf(v.w - mx);
        float s = e.x + e.y + e.z + e.w;
        #pragma unroll
        for (int off = 1; off < 64; off <<= 1) s += __shfl_xor(s, off, 64);
        const float inv = 1.f / s;
        float4 o;
        o.x = e.x * inv; o.y = e.y * inv; o.z = e.z * inv; o.w = e.w * inv;
        *(float4*)&out[(size_t)(b * NN + n0 + w) * NN + lane * 4] = o;
    }
}

extern "C" void kernel_launch(void* const* d_in, const int* in_sizes, int n_in,
                              void* d_out, int out_size, void* d_ws, size_t ws_size,
                              hipStream_t stream) {
    const float* feat  = (const float*)d_in[0];
    const float* gfeat = (const float*)d_in[1];
    const float* adj   = (const float*)d_in[2];
    const float* Wf    = (const float*)d_in[3];
    const float* bf    = (const float*)d_in[4];
    const float* Wg    = (const float*)d_in[5];
    const float* bg    = (const float*)d_in[6];
    const float* Cf    = (const float*)d_in[7];
    const float* Cg    = (const float*)d_in[9];
    const float* a_w   = (const float*)d_in[11];
    float* out = (float*)d_out;

    float* pf   = (float*)d_ws;                    // [ROWS][HID]
    float* pg   = pf + (size_t)ROWS * HID;         // [ROWS][HID]
    float* scfg = pg + (size_t)ROWS * HID;         // [2*HID]

    void* args[] = {&feat, &gfeat, &adj, &Wf, &bf, &Wg, &bg, &Cf, &Cg, &a_w,
                    &pf, &pg, &scfg, &out};
    hipLaunchCooperativeKernel((const void*)fused_kernel, dim3(256), dim3(512),
                               args, 0, stream);
}

// Round 8
// 46.463 us; speedup vs baseline: 2.7111x; 2.7111x over previous
//
#include <hip/hip_runtime.h>
#include <math.h>

#define BB 4
#define NN 256
#define FCH 512
#define GCH 256
#define HID 128
#define ROWS 1024

// ---------------- kernel 1: fused projection (f and g) + scf/scg (R5 verbatim) ----------------
template <int INCH>
__device__ __forceinline__ void proj_body(const float* __restrict__ in,
                                          const float* __restrict__ W,
                                          const float* __restrict__ bias,
                                          float* __restrict__ dst,
                                          int r0, int hh, int t,
                                          float* __restrict__ srow,
                                          float* __restrict__ partial) {
    #pragma unroll
    for (int i = 4 * t; i < 8 * INCH; i += 4 * 256)
        *(float4*)&srow[i] = *(const float4*)&in[(size_t)r0 * INCH + i];
    __syncthreads();

    const int kq = t >> 5;
    const int hp = t & 31;
    const int h = hh + hp * 2;
    constexpr int cpk = INCH / 8;
    const int c0 = kq * cpk;

    float acc[8][2];
    #pragma unroll
    for (int r = 0; r < 8; ++r) { acc[r][0] = 0.f; acc[r][1] = 0.f; }

    #pragma unroll 4
    for (int cc = 0; cc < cpk; cc += 4) {
        const int c = c0 + cc;
        const float2 w0 = *(const float2*)&W[(size_t)(c + 0) * HID + h];
        const float2 w1 = *(const float2*)&W[(size_t)(c + 1) * HID + h];
        const float2 w2 = *(const float2*)&W[(size_t)(c + 2) * HID + h];
        const float2 w3 = *(const float2*)&W[(size_t)(c + 3) * HID + h];
        #pragma unroll
        for (int r = 0; r < 8; ++r) {
            const float4 s = *(const float4*)&srow[r * INCH + c];
            acc[r][0] = fmaf(s.x, w0.x, acc[r][0]); acc[r][1] = fmaf(s.x, w0.y, acc[r][1]);
            acc[r][0] = fmaf(s.y, w1.x, acc[r][0]); acc[r][1] = fmaf(s.y, w1.y, acc[r][1]);
            acc[r][0] = fmaf(s.z, w2.x, acc[r][0]); acc[r][1] = fmaf(s.z, w2.y, acc[r][1]);
            acc[r][0] = fmaf(s.w, w3.x, acc[r][0]); acc[r][1] = fmaf(s.w, w3.y, acc[r][1]);
        }
    }

    #pragma unroll
    for (int r = 0; r < 8; ++r) {
        acc[r][0] += __shfl_xor(acc[r][0], 32, 64);
        acc[r][1] += __shfl_xor(acc[r][1], 32, 64);
    }
    const int w = t >> 6;
    if ((t & 63) < 32) {
        #pragma unroll
        for (int r = 0; r < 8; ++r)
            *(float2*)&partial[(((w * 8 + r) * 32) + hp) * 2] = *(float2*)&acc[r][0];
    }
    __syncthreads();

    {
        const int r = t >> 5;
        const int hp2 = t & 31;
        const int h2 = hh + hp2 * 2;
        float2 s = *(const float2*)&bias[h2];
        #pragma unroll
        for (int ww = 0; ww < 4; ++ww) {
            const float2 p = *(const float2*)&partial[(((ww * 8 + r) * 32) + hp2) * 2];
            s.x += p.x; s.y += p.y;
        }
        *(float2*)&dst[(size_t)(r0 + r) * HID + h2] = s;
    }
}

__global__ __launch_bounds__(256) void proj_fg_kernel(
    const float* __restrict__ feat, const float* __restrict__ gfeat,
    const float* __restrict__ Wf, const float* __restrict__ bf,
    const float* __restrict__ Wg, const float* __restrict__ bg,
    const float* __restrict__ Cf, const float* __restrict__ Cg,
    const float* __restrict__ a_w,
    float* __restrict__ pf, float* __restrict__ pg, float* __restrict__ scfg)
{
    __shared__ __align__(16) float srow[8 * FCH];
    __shared__ __align__(16) float partial[4 * 8 * 32 * 2];
    const int t = threadIdx.x;
    const int bx = blockIdx.x;
    if (bx == 0) {
        const float* C = (t < HID) ? Cf : Cg;
        const int h = t & (HID - 1);
        float a0 = 0.f, a1 = 0.f, a2 = 0.f, a3 = 0.f;
        #pragma unroll 4
        for (int k = 0; k < HID; k += 4) {
            a0 = fmaf(a_w[k + 0], C[(k + 0) * HID + h], a0);
            a1 = fmaf(a_w[k + 1], C[(k + 1) * HID + h], a1);
            a2 = fmaf(a_w[k + 2], C[(k + 2) * HID + h], a2);
            a3 = fmaf(a_w[k + 3], C[(k + 3) * HID + h], a3);
        }
        scfg[t] = (a0 + a1) + (a2 + a3);
        return;
    }
    if (bx <= 256) {
        const int blk = bx - 1;
        proj_body<FCH>(feat, Wf, bf, pf, (blk >> 1) * 8, (blk & 1) * 64, t, srow, partial);
    } else {
        const int blk = bx - 257;
        proj_body<GCH>(gfeat, Wg, bg, pg, (blk >> 1) * 8, (blk & 1) * 64, t, srow, partial);
    }
}

// ---------------- DPP 8-lane sum (valid at lanes with (lane&7)==0) ----------------
// row_shr:N => dest i = src i-N (data moves to higher lanes); row_shl:N => dest i = src i+N.
// We need lane0<-lane4, lane8<-lane12: row_shl:4 = ctrl 0x104 (out-of-row lanes -> 0 via bound_ctrl).
template <int CTRL>
__device__ __forceinline__ float dpp_add(float x) {
    const int p = __builtin_amdgcn_update_dpp(0, __float_as_int(x), CTRL, 0xF, 0xF, true);
    return x + __int_as_float(p);
}
__device__ __forceinline__ float red8(float x) {
    x = dpp_add<0xB1>(x);    // quad_perm(1,0,3,2)  = xor 1
    x = dpp_add<0x4E>(x);    // quad_perm(2,3,0,1)  = xor 2
    x = dpp_add<0x104>(x);   // row_shl:4           = lane i += lane i+4 (valid at lane&7==0)
    return x;
}

// ---------------- kernel 2: att + masked softmax, 4n x 4m register tile ----------------
// block = 512 thr = 64 m-groups(4m) x 8 h-slices(16h); grid = BB*64 (4 n-rows per block)
// USTR=20: 80B stride -> 16B-aligned b128 frags, hs*20 mod 32 hits 8 distinct bank-quads
#define USTR 20
#define JSTR (8 * USTR)

__global__ __launch_bounds__(512, 2) void att_kernel(
    const float* __restrict__ pf, const float* __restrict__ pg,
    const float* __restrict__ adj, const float* __restrict__ scfg,
    float* __restrict__ out)
{
    __shared__ __align__(16) float u_f[4 * JSTR], u_g[4 * JSTR];
    __shared__ __align__(16) float scf_l[JSTR], scg_l[JSTR];
    __shared__ __align__(16) float att_s[4][NN];

    const int t = threadIdx.x;
    const int b = blockIdx.x >> 6;
    const int n0 = (blockIdx.x & 63) * 4;

    // stage plain u rows (4 x 128) + scf/scg frags, frag-padded layout
    {
        const int j = t >> 7;
        const int h = t & (HID - 1);
        const int ui = j * JSTR + (h >> 4) * USTR + (h & 15);
        u_f[ui] = pf[(size_t)(b * NN + n0 + j) * HID + h];
        u_g[ui] = pg[(size_t)(b * NN + n0 + j) * HID + h];
        if (j == 0) {
            const int si = (h >> 4) * USTR + (h & 15);
            scf_l[si] = scfg[h];
            scg_l[si] = scfg[HID + h];
        }
    }
    __syncthreads();

    const int hs = t & 7;
    const int mg = t >> 3;
    const int m0 = mg * 4;
    const int hbase = hs * 16;

    float numf[4][4] = {}, denf[4][4] = {}, numg[4][4] = {}, deng[4][4] = {};

    #pragma unroll
    for (int it = 0; it < 4; ++it) {
        const int h = hbase + it * 4;
        float4 vf[4], vg[4], wf[4], wg[4];
        #pragma unroll
        for (int k = 0; k < 4; ++k) {
            vf[k] = *(const float4*)&pf[(size_t)(b * NN + m0 + k) * HID + h];
            vg[k] = *(const float4*)&pg[(size_t)(b * NN + m0 + k) * HID + h];
            wf[k].x = vf[k].x * vf[k].x; wf[k].y = vf[k].y * vf[k].y;
            wf[k].z = vf[k].z * vf[k].z; wf[k].w = vf[k].w * vf[k].w;
            wg[k].x = vg[k].x * vg[k].x; wg[k].y = vg[k].y * vg[k].y;
            wg[k].z = vg[k].z * vg[k].z; wg[k].w = vg[k].w * vg[k].w;
        }
        const int ub = hs * USTR + it * 4;
        const float4 sf = *(const float4*)&scf_l[ub];
        const float4 sg = *(const float4*)&scg_l[ub];
        #pragma unroll
        for (int j = 0; j < 4; ++j) {
            const float4 a4 = *(const float4*)&u_f[j * JSTR + ub];
            const float4 b4 = *(const float4*)&u_g[j * JSTR + ub];
            float4 c, q, d, r;
            c.x = a4.x * sf.x; c.y = a4.y * sf.y; c.z = a4.z * sf.z; c.w = a4.w * sf.w;
            q.x = a4.x * a4.x; q.y = a4.y * a4.y; q.z = a4.z * a4.z; q.w = a4.w * a4.w;
            d.x = b4.x * sg.x; d.y = b4.y * sg.y; d.z = b4.z * sg.z; d.w = b4.w * sg.w;
            r.x = b4.x * b4.x; r.y = b4.y * b4.y; r.z = b4.z * b4.z; r.w = b4.w * b4.w;
            #pragma unroll
            for (int k = 0; k < 4; ++k) {
                numf[j][k] = fmaf(vf[k].x, c.x, numf[j][k]);
                numf[j][k] = fmaf(vf[k].y, c.y, numf[j][k]);
                numf[j][k] = fmaf(vf[k].z, c.z, numf[j][k]);
                numf[j][k] = fmaf(vf[k].w, c.w, numf[j][k]);
                denf[j][k] = fmaf(wf[k].x, q.x, denf[j][k]);
                denf[j][k] = fmaf(wf[k].y, q.y, denf[j][k]);
                denf[j][k] = fmaf(wf[k].z, q.z, denf[j][k]);
                denf[j][k] = fmaf(wf[k].w, q.w, denf[j][k]);
                numg[j][k] = fmaf(vg[k].x, d.x, numg[j][k]);
                numg[j][k] = fmaf(vg[k].y, d.y, numg[j][k]);
                numg[j][k] = fmaf(vg[k].z, d.z, numg[j][k]);
                numg[j][k] = fmaf(vg[k].w, d.w, numg[j][k]);
                deng[j][k] = fmaf(wg[k].x, r.x, deng[j][k]);
                deng[j][k] = fmaf(wg[k].y, r.y, deng[j][k]);
                deng[j][k] = fmaf(wg[k].z, r.z, deng[j][k]);
                deng[j][k] = fmaf(wg[k].w, r.w, deng[j][k]);
            }
        }
    }

    // reduce across the 8 h-slices: pure-VALU DPP (no DS traffic)
    #pragma unroll
    for (int j = 0; j < 4; ++j) {
        #pragma unroll
        for (int k = 0; k < 4; ++k) {
            numf[j][k] = red8(numf[j][k]);
            denf[j][k] = red8(denf[j][k]);
            numg[j][k] = red8(numg[j][k]);
            deng[j][k] = red8(deng[j][k]);
        }
    }

    if (hs == 0) {
        #pragma unroll
        for (int j = 0; j < 4; ++j) {
            const float4 ad = *(const float4*)&adj[(size_t)(b * NN + n0 + j) * NN + m0];
            float4 a4;
            a4.x = numf[j][0] / fmaxf(sqrtf(denf[j][0]), 1e-12f) + numg[j][0] / fmaxf(sqrtf(deng[j][0]), 1e-12f);
            a4.y = numf[j][1] / fmaxf(sqrtf(denf[j][1]), 1e-12f) + numg[j][1] / fmaxf(sqrtf(deng[j][1]), 1e-12f);
            a4.z = numf[j][2] / fmaxf(sqrtf(denf[j][2]), 1e-12f) + numg[j][2] / fmaxf(sqrtf(deng[j][2]), 1e-12f);
            a4.w = numf[j][3] / fmaxf(sqrtf(denf[j][3]), 1e-12f) + numg[j][3] / fmaxf(sqrtf(deng[j][3]), 1e-12f);
            if (ad.x == 0.f) a4.x -= 1e22f;
            if (ad.y == 0.f) a4.y -= 1e22f;
            if (ad.z == 0.f) a4.z -= 1e22f;
            if (ad.w == 0.f) a4.w -= 1e22f;
            *(float4*)&att_s[j][m0] = a4;
        }
    }
    __syncthreads();

    const int w = t >> 6;
    const int lane = t & 63;
    if (w < 4) {
        const float4 v = *(const float4*)&att_s[w][lane * 4];
        float mx = fmaxf(fmaxf(v.x, v.y), fmaxf(v.z, v.w));
        #pragma unroll
        for (int off = 1; off < 64; off <<= 1) mx = fmaxf(mx, __shfl_xor(mx, off, 64));
        float4 e;
        e.x = __expf(v.x - mx); e.y = __expf(v.y - mx);
        e.z = __expf(v.z - mx); e.w = __expf(v.w - mx);
        float s = e.x + e.y + e.z + e.w;
        #pragma unroll
        for (int off = 1; off < 64; off <<= 1) s += __shfl_xor(s, off, 64);
        const float inv = 1.f / s;
        float4 o;
        o.x = e.x * inv; o.y = e.y * inv; o.z = e.z * inv; o.w = e.w * inv;
        *(float4*)&out[(size_t)(b * NN + n0 + w) * NN + lane * 4] = o;
    }
}

extern "C" void kernel_launch(void* const* d_in, const int* in_sizes, int n_in,
                              void* d_out, int out_size, void* d_ws, size_t ws_size,
                              hipStream_t stream) {
    const float* feat  = (const float*)d_in[0];
    const float* gfeat = (const float*)d_in[1];
    const float* adj   = (const float*)d_in[2];
    const float* Wf    = (const float*)d_in[3];
    const float* bf    = (const float*)d_in[4];
    const float* Wg    = (const float*)d_in[5];
    const float* bg    = (const float*)d_in[6];
    const float* Cf    = (const float*)d_in[7];
    const float* Cg    = (const float*)d_in[9];
    const float* a_w   = (const float*)d_in[11];
    float* out = (float*)d_out;

    float* pf   = (float*)d_ws;                    // [ROWS][HID]
    float* pg   = pf + (size_t)ROWS * HID;         // [ROWS][HID]
    float* scfg = pg + (size_t)ROWS * HID;         // [2*HID]

    proj_fg_kernel<<<513, 256, 0, stream>>>(feat, gfeat, Wf, bf, Wg, bg,
                                            Cf, Cg, a_w, pf, pg, scfg);
    att_kernel<<<BB * 64, 512, 0, stream>>>(pf, pg, adj, scfg, out);
}

// Round 9
// 28.595 us; speedup vs baseline: 4.4051x; 1.6248x over previous
//
#include <hip/hip_runtime.h>
#include <math.h>

#define BB 4
#define NN 256
#define FCH 512
#define GCH 256
#define HID 128
#define ROWS 1024

// ---------------- kernel 1: fused projection (f and g) + scf/scg (R5 verbatim) ----------------
template <int INCH>
__device__ __forceinline__ void proj_body(const float* __restrict__ in,
                                          const float* __restrict__ W,
                                          const float* __restrict__ bias,
                                          float* __restrict__ dst,
                                          int r0, int hh, int t,
                                          float* __restrict__ srow,
                                          float* __restrict__ partial) {
    #pragma unroll
    for (int i = 4 * t; i < 8 * INCH; i += 4 * 256)
        *(float4*)&srow[i] = *(const float4*)&in[(size_t)r0 * INCH + i];
    __syncthreads();

    const int kq = t >> 5;
    const int hp = t & 31;
    const int h = hh + hp * 2;
    constexpr int cpk = INCH / 8;
    const int c0 = kq * cpk;

    float acc[8][2];
    #pragma unroll
    for (int r = 0; r < 8; ++r) { acc[r][0] = 0.f; acc[r][1] = 0.f; }

    #pragma unroll 4
    for (int cc = 0; cc < cpk; cc += 4) {
        const int c = c0 + cc;
        const float2 w0 = *(const float2*)&W[(size_t)(c + 0) * HID + h];
        const float2 w1 = *(const float2*)&W[(size_t)(c + 1) * HID + h];
        const float2 w2 = *(const float2*)&W[(size_t)(c + 2) * HID + h];
        const float2 w3 = *(const float2*)&W[(size_t)(c + 3) * HID + h];
        #pragma unroll
        for (int r = 0; r < 8; ++r) {
            const float4 s = *(const float4*)&srow[r * INCH + c];
            acc[r][0] = fmaf(s.x, w0.x, acc[r][0]); acc[r][1] = fmaf(s.x, w0.y, acc[r][1]);
            acc[r][0] = fmaf(s.y, w1.x, acc[r][0]); acc[r][1] = fmaf(s.y, w1.y, acc[r][1]);
            acc[r][0] = fmaf(s.z, w2.x, acc[r][0]); acc[r][1] = fmaf(s.z, w2.y, acc[r][1]);
            acc[r][0] = fmaf(s.w, w3.x, acc[r][0]); acc[r][1] = fmaf(s.w, w3.y, acc[r][1]);
        }
    }

    #pragma unroll
    for (int r = 0; r < 8; ++r) {
        acc[r][0] += __shfl_xor(acc[r][0], 32, 64);
        acc[r][1] += __shfl_xor(acc[r][1], 32, 64);
    }
    const int w = t >> 6;
    if ((t & 63) < 32) {
        #pragma unroll
        for (int r = 0; r < 8; ++r)
            *(float2*)&partial[(((w * 8 + r) * 32) + hp) * 2] = *(float2*)&acc[r][0];
    }
    __syncthreads();

    {
        const int r = t >> 5;
        const int hp2 = t & 31;
        const int h2 = hh + hp2 * 2;
        float2 s = *(const float2*)&bias[h2];
        #pragma unroll
        for (int ww = 0; ww < 4; ++ww) {
            const float2 p = *(const float2*)&partial[(((ww * 8 + r) * 32) + hp2) * 2];
            s.x += p.x; s.y += p.y;
        }
        *(float2*)&dst[(size_t)(r0 + r) * HID + h2] = s;
    }
}

__global__ __launch_bounds__(256) void proj_fg_kernel(
    const float* __restrict__ feat, const float* __restrict__ gfeat,
    const float* __restrict__ Wf, const float* __restrict__ bf,
    const float* __restrict__ Wg, const float* __restrict__ bg,
    const float* __restrict__ Cf, const float* __restrict__ Cg,
    const float* __restrict__ a_w,
    float* __restrict__ pf, float* __restrict__ pg, float* __restrict__ scfg)
{
    __shared__ __align__(16) float srow[8 * FCH];
    __shared__ __align__(16) float partial[4 * 8 * 32 * 2];
    const int t = threadIdx.x;
    const int bx = blockIdx.x;
    if (bx == 0) {
        const float* C = (t < HID) ? Cf : Cg;
        const int h = t & (HID - 1);
        float a0 = 0.f, a1 = 0.f, a2 = 0.f, a3 = 0.f;
        #pragma unroll 4
        for (int k = 0; k < HID; k += 4) {
            a0 = fmaf(a_w[k + 0], C[(k + 0) * HID + h], a0);
            a1 = fmaf(a_w[k + 1], C[(k + 1) * HID + h], a1);
            a2 = fmaf(a_w[k + 2], C[(k + 2) * HID + h], a2);
            a3 = fmaf(a_w[k + 3], C[(k + 3) * HID + h], a3);
        }
        scfg[t] = (a0 + a1) + (a2 + a3);
        return;
    }
    if (bx <= 256) {
        const int blk = bx - 1;
        proj_body<FCH>(feat, Wf, bf, pf, (blk >> 1) * 8, (blk & 1) * 64, t, srow, partial);
    } else {
        const int blk = bx - 257;
        proj_body<GCH>(gfeat, Wg, bg, pg, (blk >> 1) * 8, (blk & 1) * 64, t, srow, partial);
    }
}

// ---------------- DPP 8-lane sum (valid at lanes with (lane&7)==0) ----------------
template <int CTRL>
__device__ __forceinline__ float dpp_add(float x) {
    const int p = __builtin_amdgcn_update_dpp(0, __float_as_int(x), CTRL, 0xF, 0xF, true);
    return x + __int_as_float(p);
}
__device__ __forceinline__ float red8(float x) {
    x = dpp_add<0xB1>(x);    // quad_perm(1,0,3,2)  = xor 1
    x = dpp_add<0x4E>(x);    // quad_perm(2,3,0,1)  = xor 2
    x = dpp_add<0x104>(x);   // row_shl:4           = lane i += lane i+4 (valid at lane&7==0)
    return x;
}

// ---------------- kernel 2: att + masked softmax, 4n x 4m register tile ----------------
// block = 512 thr = 64 m-groups(4m) x 8 h-slices(16h); grid = BB*64 (4 n-rows per block)
// USTR=40: 160B stride -> 16B-aligned (true ds_read_b128); hs*40 mod 32 in {0,8,16,24}
// -> at most 2-way bank aliasing (free). Derived arrays built at staging (low loop VGPR).
#define USTR 40
#define JSTR (8 * USTR)
#define UIDX(j, h) ((j) * JSTR + ((h) >> 4) * USTR + ((h) & 15))

__global__ __launch_bounds__(512, 2) void att_kernel(
    const float* __restrict__ pf, const float* __restrict__ pg,
    const float* __restrict__ adj, const float* __restrict__ scfg,
    float* __restrict__ out)
{
    __shared__ __align__(16) float ufc[4 * JSTR], uf2s[4 * JSTR];
    __shared__ __align__(16) float ugc[4 * JSTR], ug2s[4 * JSTR];
    __shared__ __align__(16) float att_s[4][NN];

    const int t = threadIdx.x;
    const int b = blockIdx.x >> 6;
    const int n0 = (blockIdx.x & 63) * 4;

    // stage u-row derived arrays (4 rows x 128 h), 16B-aligned padded layout
    {
        const int j = t >> 7;
        const int h = t & (HID - 1);
        const float sf = scfg[h];
        const float sg = scfg[HID + h];
        const float uf = pf[(size_t)(b * NN + n0 + j) * HID + h];
        const float ug = pg[(size_t)(b * NN + n0 + j) * HID + h];
        const int ui = UIDX(j, h);
        ufc[ui]  = uf * sf;
        uf2s[ui] = uf * uf;
        ugc[ui]  = ug * sg;
        ug2s[ui] = ug * ug;
    }
    __syncthreads();

    const int hs = t & 7;
    const int mg = t >> 3;
    const int m0 = mg * 4;
    const int hbase = hs * 16;

    float numf[4][4] = {}, denf[4][4] = {}, numg[4][4] = {}, deng[4][4] = {};

    #pragma unroll
    for (int it = 0; it < 4; ++it) {
        const int h = hbase + it * 4;
        float4 vf[4], vg[4], wf[4], wg[4];
        #pragma unroll
        for (int k = 0; k < 4; ++k) {
            vf[k] = *(const float4*)&pf[(size_t)(b * NN + m0 + k) * HID + h];
            vg[k] = *(const float4*)&pg[(size_t)(b * NN + m0 + k) * HID + h];
            wf[k].x = vf[k].x * vf[k].x; wf[k].y = vf[k].y * vf[k].y;
            wf[k].z = vf[k].z * vf[k].z; wf[k].w = vf[k].w * vf[k].w;
            wg[k].x = vg[k].x * vg[k].x; wg[k].y = vg[k].y * vg[k].y;
            wg[k].z = vg[k].z * vg[k].z; wg[k].w = vg[k].w * vg[k].w;
        }
        #pragma unroll
        for (int j = 0; j < 4; ++j) {
            const int ui = j * JSTR + hs * USTR + it * 4;
            const float4 c = *(const float4*)&ufc[ui];
            const float4 q = *(const float4*)&uf2s[ui];
            const float4 d = *(const float4*)&ugc[ui];
            const float4 r = *(const float4*)&ug2s[ui];
            #pragma unroll
            for (int k = 0; k < 4; ++k) {
                numf[j][k] = fmaf(vf[k].x, c.x, numf[j][k]);
                numf[j][k] = fmaf(vf[k].y, c.y, numf[j][k]);
                numf[j][k] = fmaf(vf[k].z, c.z, numf[j][k]);
                numf[j][k] = fmaf(vf[k].w, c.w, numf[j][k]);
                denf[j][k] = fmaf(wf[k].x, q.x, denf[j][k]);
                denf[j][k] = fmaf(wf[k].y, q.y, denf[j][k]);
                denf[j][k] = fmaf(wf[k].z, q.z, denf[j][k]);
                denf[j][k] = fmaf(wf[k].w, q.w, denf[j][k]);
                numg[j][k] = fmaf(vg[k].x, d.x, numg[j][k]);
                numg[j][k] = fmaf(vg[k].y, d.y, numg[j][k]);
                numg[j][k] = fmaf(vg[k].z, d.z, numg[j][k]);
                numg[j][k] = fmaf(vg[k].w, d.w, numg[j][k]);
                deng[j][k] = fmaf(wg[k].x, r.x, deng[j][k]);
                deng[j][k] = fmaf(wg[k].y, r.y, deng[j][k]);
                deng[j][k] = fmaf(wg[k].z, r.z, deng[j][k]);
                deng[j][k] = fmaf(wg[k].w, r.w, deng[j][k]);
            }
        }
    }

    // reduce across the 8 h-slices: pure-VALU DPP (no DS traffic)
    #pragma unroll
    for (int j = 0; j < 4; ++j) {
        #pragma unroll
        for (int k = 0; k < 4; ++k) {
            numf[j][k] = red8(numf[j][k]);
            denf[j][k] = red8(denf[j][k]);
            numg[j][k] = red8(numg[j][k]);
            deng[j][k] = red8(deng[j][k]);
        }
    }

    if (hs == 0) {
        #pragma unroll
        for (int j = 0; j < 4; ++j) {
            const float4 ad = *(const float4*)&adj[(size_t)(b * NN + n0 + j) * NN + m0];
            float4 a4;
            a4.x = numf[j][0] / fmaxf(sqrtf(denf[j][0]), 1e-12f) + numg[j][0] / fmaxf(sqrtf(deng[j][0]), 1e-12f);
            a4.y = numf[j][1] / fmaxf(sqrtf(denf[j][1]), 1e-12f) + numg[j][1] / fmaxf(sqrtf(deng[j][1]), 1e-12f);
            a4.z = numf[j][2] / fmaxf(sqrtf(denf[j][2]), 1e-12f) + numg[j][2] / fmaxf(sqrtf(deng[j][2]), 1e-12f);
            a4.w = numf[j][3] / fmaxf(sqrtf(denf[j][3]), 1e-12f) + numg[j][3] / fmaxf(sqrtf(deng[j][3]), 1e-12f);
            if (ad.x == 0.f) a4.x -= 1e22f;
            if (ad.y == 0.f) a4.y -= 1e22f;
            if (ad.z == 0.f) a4.z -= 1e22f;
            if (ad.w == 0.f) a4.w -= 1e22f;
            *(float4*)&att_s[j][m0] = a4;
        }
    }
    __syncthreads();

    const int w = t >> 6;
    const int lane = t & 63;
    if (w < 4) {
        const float4 v = *(const float4*)&att_s[w][lane * 4];
        float mx = fmaxf(fmaxf(v.x, v.y), fmaxf(v.z, v.w));
        #pragma unroll
        for (int off = 1; off < 64; off <<= 1) mx = fmaxf(mx, __shfl_xor(mx, off, 64));
        float4 e;
        e.x = __expf(v.x - mx); e.y = __expf(v.y - mx);
        e.z = __expf(v.z - mx); e.w = __expf(v.w - mx);
        float s = e.x + e.y + e.z + e.w;
        #pragma unroll
        for (int off = 1; off < 64; off <<= 1) s += __shfl_xor(s, off, 64);
        const float inv = 1.f / s;
        float4 o;
        o.x = e.x * inv; o.y = e.y * inv; o.z = e.z * inv; o.w = e.w * inv;
        *(float4*)&out[(size_t)(b * NN + n0 + w) * NN + lane * 4] = o;
    }
}

extern "C" void kernel_launch(void* const* d_in, const int* in_sizes, int n_in,
                              void* d_out, int out_size, void* d_ws, size_t ws_size,
                              hipStream_t stream) {
    const float* feat  = (const float*)d_in[0];
    const float* gfeat = (const float*)d_in[1];
    const float* adj   = (const float*)d_in[2];
    const float* Wf    = (const float*)d_in[3];
    const float* bf    = (const float*)d_in[4];
    const float* Wg    = (const float*)d_in[5];
    const float* bg    = (const float*)d_in[6];
    const float* Cf    = (const float*)d_in[7];
    const float* Cg    = (const float*)d_in[9];
    const float* a_w   = (const float*)d_in[11];
    float* out = (float*)d_out;

    float* pf   = (float*)d_ws;                    // [ROWS][HID]
    float* pg   = pf + (size_t)ROWS * HID;         // [ROWS][HID]
    float* scfg = pg + (size_t)ROWS * HID;         // [2*HID]

    proj_fg_kernel<<<513, 256, 0, stream>>>(feat, gfeat, Wf, bf, Wg, bg,
                                            Cf, Cg, a_w, pf, pg, scfg);
    att_kernel<<<BB * 64, 512, 0, stream>>>(pf, pg, adj, scfg, out);
}